// Round 3
// baseline (288.579 us; speedup 1.0000x reference)
//
#include <hip/hip_runtime.h>
#include <math.h>

// B=8, C=64, H=W=256. conv_sigma: OC=32, VALID 3x3 -> 254x254 (bf16 MFMA).
// blur: stride 2, reflect pad 1, sigma/kern precomputed by sigma_kernel.
//
// BIG-WS path (ws >= ~68MB):
//   prep_cvt: x fp32 [b][ic][y][x] -> xbf bf16 [b][y][x][ic] (67MB in ws) + wtb prep.
//   conv_lds: stages tiles via global_load_lds dwordx4 (no VALU, linear LDS dest,
//             swizzle via pre-swizzled SOURCE octet per guide m173/m201).
// SMALL-WS fallback: previous reg-staged conv (proven).
//
// ws float layout: acc[0,256) ; kparams [256,288) ; wtb bf16 @ 512 (9216 floats)
//                  xbf bf16 @ float-ofs 16384 (16.78M floats)

typedef __attribute__((ext_vector_type(8))) short s8v;   // 8 bf16
typedef __attribute__((ext_vector_type(4))) float f4v;   // 4 f32

static __device__ inline unsigned short f2bf(float f) {
    union { float f; unsigned int u; } v; v.f = f;
    unsigned int u = v.u;
    unsigned int r = u + 0x7FFFu + ((u >> 16) & 1u);
    return (unsigned short)(r >> 16);
}

// pack 2 f32 -> 2 bf16 (RNE) in one instruction; lo = a, hi = b
static __device__ inline unsigned int pk_bf16(float a, float b) {
    unsigned int r;
    asm("v_cvt_pk_bf16_f32 %0, %1, %2" : "=v"(r) : "v"(a), "v"(b));
    return r;
}

// ==================== BIG-WS PATH ====================

// ---- prep_cvt: blocks 0..8191 transpose-convert x; block 8192 does weight prep ----
// cvt block: b = blk>>10, 64-pixel span P0 = (blk&1023)*64, all 64 ic.
// LDS 64ic x 64px bf16 (8KB), 8B-chunk XOR swizzle (slot = chunk ^ (ic&15)).
__global__ __launch_bounds__(256) void prep_cvt_kernel(
        const float* __restrict__ x, const float* __restrict__ w,
        float* __restrict__ ws, unsigned short* __restrict__ xbf) {
    const int blk = blockIdx.x;
    const int tid = threadIdx.x;
    if (blk >= 8192) {
        if (tid < 256) ws[tid] = 0.f;
        unsigned short* wtb = (unsigned short*)(ws + 512);
        for (int i = tid; i < 9 * 32 * 64; i += 256) {
            int ic  = i & 63;
            int oc  = (i >> 6) & 31;
            int tap = i >> 11;
            wtb[i] = f2bf(w[oc * 576 + ic * 9 + tap]);
        }
        return;
    }
    __shared__ __align__(16) unsigned short sld[4096];   // 8 KB
    const int b  = blk >> 10;
    const int P0 = (blk & 1023) * 64;
    const float* xb = x + (size_t)b * 64 * 65536;

    const int c = tid & 15, r = tid >> 4;     // chunk (4px), ic subrow
#pragma unroll
    for (int kk = 0; kk < 4; ++kk) {
        int ic = kk * 16 + r;
        float4 v = *(const float4*)(xb + (size_t)ic * 65536 + P0 + 4 * c);
        unsigned int u0 = pk_bf16(v.x, v.y);
        unsigned int u1 = pk_bf16(v.z, v.w);
        int slot = c ^ r;                      // r == ic&15 for all kk
        *(uint2*)((unsigned char*)sld + ic * 128 + slot * 8) = make_uint2(u0, u1);
    }
    __syncthreads();

    const int l = tid & 63, wv = tid >> 6;
    const int oct = l & 7;
#pragma unroll
    for (int k2 = 0; k2 < 2; ++k2) {
        int px = wv * 16 + k2 * 8 + (l >> 3);
        unsigned int lo0, lo1, hi0, hi1;
        unsigned short us[8];
#pragma unroll
        for (int i = 0; i < 8; ++i) {
            int ic = oct * 8 + i;
            int slot = (px >> 2) ^ (ic & 15);
            us[i] = *(const unsigned short*)((unsigned char*)sld + ic * 128 + slot * 8 + (px & 3) * 2);
        }
        uint4 o4;
        o4.x = (unsigned int)us[0] | ((unsigned int)us[1] << 16);
        o4.y = (unsigned int)us[2] | ((unsigned int)us[3] << 16);
        o4.z = (unsigned int)us[4] | ((unsigned int)us[5] << 16);
        o4.w = (unsigned int)us[6] | ((unsigned int)us[7] << 16);
        *(uint4*)(xbf + (((size_t)b * 65536 + P0 + px) * 64 + oct * 8)) = o4;
    }
}

// ---- conv via global_load_lds ----
// grid (8 bx, 32 by, 8 b), block 256 = 4 waves. Block: 8 oy x 32 ox x 32 oc.
// LDS: 10 rows x 36 px x 128B (46080 B), 16B chunks; chunk s of pixel p holds
// source ic-octet o = s ^ ((p>>1)&7)  (swizzle applied on SOURCE address;
// LDS dest is linear as global_load_lds requires). Read slot = o ^ ((p>>1)&7).
__global__ __launch_bounds__(256, 3) void conv_lds_kernel(
        const unsigned short* __restrict__ xbf,
        const unsigned short* __restrict__ wtb,
        float* __restrict__ acc_out) {
    __shared__ __align__(16) unsigned char sx[360 * 128];  // 46080 B
    __shared__ float sred[4][32];

    const int bx = blockIdx.x, by = blockIdx.y, b = blockIdx.z;
    const int ox0 = bx * 32, oy0 = by * 8;
    const int tid = threadIdx.x;
    const int lane = tid & 63, w = tid >> 6;
    const int m = lane & 15, q = lane >> 4;

    // B-frag prefetch for tap 0 (drains at barrier with the stage loads)
    const unsigned short* wB = wtb + m * 64 + q * 8;
    s8v bc0 = *(const s8v*)(wB);               // kc0, oc m
    s8v bc1 = *(const s8v*)(wB + 1024);        // kc0, oc 16+m
    s8v bc2 = *(const s8v*)(wB + 32);          // kc1, oc m
    s8v bc3 = *(const s8v*)(wB + 1024 + 32);   // kc1, oc 16+m

    // ---- stage: 45 x global_load_lds dwordx4 (wave w takes cg ≡ w mod 4) ----
    const unsigned short* xb = xbf + (size_t)b * (65536 * 64);
#pragma unroll
    for (int cg0 = 0; cg0 < 48; cg0 += 4) {
        int cg = cg0 + w;
        if (cg < 45) {                         // wave-uniform guard
            int g = cg * 64 + lane;            // global 16B-chunk id
            int p = g >> 3, s = g & 7;         // pixel, dest slot
            int yy = p / 36;                   // magic-mul div
            int xx = p - yy * 36;
            int y  = oy0 + yy;  if (y  > 255) y  = 255;   // clamped slots feed
            int xc = ox0 + xx;  if (xc > 255) xc = 255;   // only masked outputs
            int o  = s ^ ((p >> 1) & 7);       // source octet (pre-swizzle)
            const unsigned short* src = xb + (((y << 8) + xc) << 6) + (o << 3);
            __builtin_amdgcn_global_load_lds(
                (const __attribute__((address_space(1))) void*)src,
                (__attribute__((address_space(3))) void*)(sx + cg * 1024),
                16, 0, 0);
        }
    }
    __syncthreads();

    // ---- K-loop: fully unrolled 9 taps, B-frags 2-deep software pipelined ----
    f4v acc[4][2];
#pragma unroll
    for (int mt = 0; mt < 4; ++mt)
#pragma unroll
        for (int nt = 0; nt < 2; ++nt) acc[mt][nt] = (f4v)0.f;

    int pb[4];
#pragma unroll
    for (int mt = 0; mt < 4; ++mt)
        pb[mt] = (2 * w + (mt >> 1)) * 36 + (mt & 1) * 16 + m;

#pragma unroll
    for (int t = 0; t < 9; ++t) {
        const int off = (t / 3) * 36 + (t % 3);   // compile-time tap offset
        s8v bn0, bn1, bn2, bn3;
        if (t < 8) {                               // compile-time branch
            const unsigned short* wN = wB + (t + 1) * 2048;
            bn0 = *(const s8v*)(wN);
            bn1 = *(const s8v*)(wN + 1024);
            bn2 = *(const s8v*)(wN + 32);
            bn3 = *(const s8v*)(wN + 1024 + 32);
        }
#pragma unroll
        for (int mt = 0; mt < 4; ++mt) {
            int p  = pb[mt] + off;
            int q0 = q ^ ((p >> 1) & 7);
            s8v afr = *(const s8v*)(sx + p * 128 + q0 * 16);
            acc[mt][0] = __builtin_amdgcn_mfma_f32_16x16x32_bf16(afr, bc0, acc[mt][0], 0, 0, 0);
            acc[mt][1] = __builtin_amdgcn_mfma_f32_16x16x32_bf16(afr, bc1, acc[mt][1], 0, 0, 0);
        }
#pragma unroll
        for (int mt = 0; mt < 4; ++mt) {
            int p  = pb[mt] + off;
            int q1 = (4 + q) ^ ((p >> 1) & 7);
            s8v afr = *(const s8v*)(sx + p * 128 + q1 * 16);
            acc[mt][0] = __builtin_amdgcn_mfma_f32_16x16x32_bf16(afr, bc2, acc[mt][0], 0, 0, 0);
            acc[mt][1] = __builtin_amdgcn_mfma_f32_16x16x32_bf16(afr, bc3, acc[mt][1], 0, 0, 0);
        }
        if (t < 8) { bc0 = bn0; bc1 = bn1; bc2 = bn2; bc3 = bn3; }
    }

    // ---- epilogue: relu + mask invalid pixels + reduce ----
    float s0 = 0.f, s1 = 0.f;
#pragma unroll
    for (int mt = 0; mt < 4; ++mt) {
        int oy = oy0 + 2 * w + (mt >> 1);
        int oxb = ox0 + (mt & 1) * 16 + q * 4;
#pragma unroll
        for (int reg = 0; reg < 4; ++reg) {
            bool val = (oxb + reg < 254) && (oy < 254);
            if (val) {
                s0 += fmaxf(acc[mt][0][reg], 0.f);
                s1 += fmaxf(acc[mt][1][reg], 0.f);
            }
        }
    }
    s0 += __shfl_xor(s0, 16, 64); s0 += __shfl_xor(s0, 32, 64);
    s1 += __shfl_xor(s1, 16, 64); s1 += __shfl_xor(s1, 32, 64);
    if (lane < 16) { sred[w][lane] = s0; sred[w][16 + lane] = s1; }
    __syncthreads();
    if (tid < 32)
        atomicAdd(&acc_out[b * 32 + tid],
                  sred[0][tid] + sred[1][tid] + sred[2][tid] + sred[3][tid]);
}

// ==================== SMALL-WS FALLBACK (round-2 conv, proven) ====================

__global__ void prep_kernel(const float* __restrict__ w, float* __restrict__ ws) {
    int i = blockIdx.x * blockDim.x + threadIdx.x;
    if (i < 256) ws[i] = 0.f;
    if (i < 9 * 32 * 64) {
        int ic  = i & 63;
        int oc  = (i >> 6) & 31;
        int tap = i >> 11;
        unsigned short* wtb = (unsigned short*)(ws + 512);
        wtb[i] = f2bf(w[oc * 576 + ic * 9 + tap]);
    }
}

__global__ __launch_bounds__(256, 3) void conv_mfma_kernel(
        const float* __restrict__ x, const unsigned short* __restrict__ wtb,
        float* __restrict__ acc_out) {
    __shared__ __align__(16) unsigned char sx[370 * 128];
    __shared__ float sred[4][32];

    const int bx = blockIdx.x, by = blockIdx.y, b = blockIdx.z;
    const int ox0 = bx * 32, oy0 = by * 8;
    const int tid = threadIdx.x;
    const int lane = tid & 63, w = tid >> 6;
    const int m = lane & 15, q = lane >> 4;

    const float* xb = x + (size_t)b * 64 * 65536;
    float4 va[6][4];
    int   pj[6];
    int   r4a[6];
    bool  vld[6];
#pragma unroll
    for (int k = 0; k < 6; ++k) {
        int i  = tid + k * 256;
        int ch = i % 9;
        int t9 = i / 9;
        int yy = t9 % 10;
        int r4 = t9 / 10;
        int y  = oy0 + yy;  if (y > 255) y = 255;
        int xc = ox0 + ch * 4;  if (xc > 252) xc = 252;
        const float* src = xb + (size_t)((r4 & 15) << 2) * 65536 + y * 256 + xc;
        va[k][0] = *(const float4*)(src);
        va[k][1] = *(const float4*)(src + 65536);
        va[k][2] = *(const float4*)(src + 131072);
        va[k][3] = *(const float4*)(src + 196608);
        pj[k]  = yy * 37 + ch * 4;
        r4a[k] = r4;
        vld[k] = (i < 1440);
    }

    const unsigned short* wB = wtb + m * 64 + q * 8;
    s8v bc0 = *(const s8v*)(wB);
    s8v bc1 = *(const s8v*)(wB + 1024);
    s8v bc2 = *(const s8v*)(wB + 32);
    s8v bc3 = *(const s8v*)(wB + 1024 + 32);

#pragma unroll
    for (int k = 0; k < 6; ++k) {
        if (vld[k]) {
            int r4 = r4a[k];
            const float* a0 = (const float*)&va[k][0];
            const float* a1 = (const float*)&va[k][1];
            const float* a2 = (const float*)&va[k][2];
            const float* a3 = (const float*)&va[k][3];
#pragma unroll
            for (int j = 0; j < 4; ++j) {
                int p = pj[k] + j;
                unsigned int lo = pk_bf16(a0[j], a1[j]);
                unsigned int hi = pk_bf16(a2[j], a3[j]);
                int cw = (r4 >> 1) ^ ((p >> 1) & 7);
                *(uint2*)(sx + p * 128 + cw * 16 + (r4 & 1) * 8) = make_uint2(lo, hi);
            }
        }
    }
    __syncthreads();

    f4v acc[4][2];
#pragma unroll
    for (int mt = 0; mt < 4; ++mt)
#pragma unroll
        for (int nt = 0; nt < 2; ++nt) acc[mt][nt] = (f4v)0.f;

    int pb[4];
#pragma unroll
    for (int mt = 0; mt < 4; ++mt)
        pb[mt] = (2 * w + (mt >> 1)) * 37 + (mt & 1) * 16 + m;

#pragma unroll
    for (int t = 0; t < 9; ++t) {
        const int off = (t / 3) * 37 + (t % 3);
        s8v bn0, bn1, bn2, bn3;
        if (t < 8) {
            const unsigned short* wN = wB + (t + 1) * 2048;
            bn0 = *(const s8v*)(wN);
            bn1 = *(const s8v*)(wN + 1024);
            bn2 = *(const s8v*)(wN + 32);
            bn3 = *(const s8v*)(wN + 1024 + 32);
        }
#pragma unroll
        for (int mt = 0; mt < 4; ++mt) {
            int p  = pb[mt] + off;
            int q0 = q ^ ((p >> 1) & 7);
            s8v afr = *(const s8v*)(sx + p * 128 + q0 * 16);
            acc[mt][0] = __builtin_amdgcn_mfma_f32_16x16x32_bf16(afr, bc0, acc[mt][0], 0, 0, 0);
            acc[mt][1] = __builtin_amdgcn_mfma_f32_16x16x32_bf16(afr, bc1, acc[mt][1], 0, 0, 0);
        }
#pragma unroll
        for (int mt = 0; mt < 4; ++mt) {
            int p  = pb[mt] + off;
            int q1 = (4 + q) ^ ((p >> 1) & 7);
            s8v afr = *(const s8v*)(sx + p * 128 + q1 * 16);
            acc[mt][0] = __builtin_amdgcn_mfma_f32_16x16x32_bf16(afr, bc2, acc[mt][0], 0, 0, 0);
            acc[mt][1] = __builtin_amdgcn_mfma_f32_16x16x32_bf16(afr, bc3, acc[mt][1], 0, 0, 0);
        }
        if (t < 8) { bc0 = bn0; bc1 = bn1; bc2 = bn2; bc3 = bn3; }
    }

    float s0 = 0.f, s1 = 0.f;
#pragma unroll
    for (int mt = 0; mt < 4; ++mt) {
        int oy = oy0 + 2 * w + (mt >> 1);
        int oxb = ox0 + (mt & 1) * 16 + q * 4;
#pragma unroll
        for (int reg = 0; reg < 4; ++reg) {
            bool val = (oxb + reg < 254) && (oy < 254);
            if (val) {
                s0 += fmaxf(acc[mt][0][reg], 0.f);
                s1 += fmaxf(acc[mt][1][reg], 0.f);
            }
        }
    }
    s0 += __shfl_xor(s0, 16, 64); s0 += __shfl_xor(s0, 32, 64);
    s1 += __shfl_xor(s1, 16, 64); s1 += __shfl_xor(s1, 32, 64);
    if (lane < 16) { sred[w][lane] = s0; sred[w][16 + lane] = s1; }
    __syncthreads();
    if (tid < 32)
        atomicAdd(&acc_out[b * 32 + tid],
                  sred[0][tid] + sred[1][tid] + sred[2][tid] + sred[3][tid]);
}

// ==================== COMMON TAIL ====================

__global__ void sigma_kernel(const float* __restrict__ acc, const float* __restrict__ wfc,
                             const float* __restrict__ bfc, float* __restrict__ kout) {
    int t = threadIdx.x;
    int b = t >> 3, j = t & 7;
    float s = 0.f;
#pragma unroll
    for (int i = 0; i < 4; ++i) s += acc[b * 32 + j + i * 8] * wfc[j + i * 8];
    s += __shfl_xor(s, 4, 8);
    s += __shfl_xor(s, 2, 8);
    s += __shfl_xor(s, 1, 8);
    if (j == 0) {
        float z = s * (1.0f / (254.0f * 254.0f)) + bfc[0];
        float sig = 1.0f / (1.0f + __expf(-z));
        float ss = fmaxf(sig, 1e-4f);
        float inv2 = 0.5f / (ss * ss);
        float e1 = __expf(-inv2);
        float e2 = __expf(-2.0f * inv2);
        float inv_norm = 1.0f / (1.0f + 4.0f * e1 + 4.0f * e2);
        kout[b * 4 + 0] = inv_norm;
        kout[b * 4 + 1] = e1 * inv_norm;
        kout[b * 4 + 2] = e2 * inv_norm;
    }
}

__global__ __launch_bounds__(256) void blur_kernel(
        const float* __restrict__ x, const float* __restrict__ kp,
        float* __restrict__ out) {
    const int c = blockIdx.z, b = blockIdx.y;
    const int tid = threadIdx.x;
    const int qx = tid & 31;
    const int oy = blockIdx.x * 8 + (tid >> 5);

    const float kC = kp[b * 4 + 0];
    const float kE = kp[b * 4 + 1];
    const float kD = kp[b * 4 + 2];

    const float* xb = x + ((size_t)(b * 64 + c)) * 65536;

    float o0 = 0.f, o1 = 0.f, o2 = 0.f, o3 = 0.f;
#pragma unroll
    for (int dy = 0; dy < 3; ++dy) {
        int iy = 2 * oy + dy - 1;
        if (iy < 0) iy = 1;
        const float* row = xb + iy * 256;
        const float4 f0 = *(const float4*)(row + 8 * qx);
        const float4 f1 = *(const float4*)(row + 8 * qx + 4);
        float lf = __shfl_up(f1.w, 1, 64);
        const float sm1 = (qx == 0) ? f0.y : lf;
        const float ka = (dy == 1) ? kE : kD;
        const float kb = (dy == 1) ? kC : kE;
        const float kc2 = (dy == 1) ? kE : kD;
        o0 = fmaf(ka, sm1,  fmaf(kb, f0.x, fmaf(kc2, f0.y, o0)));
        o1 = fmaf(ka, f0.y, fmaf(kb, f0.z, fmaf(kc2, f0.w, o1)));
        o2 = fmaf(ka, f0.w, fmaf(kb, f1.x, fmaf(kc2, f1.y, o2)));
        o3 = fmaf(ka, f1.y, fmaf(kb, f1.z, fmaf(kc2, f1.w, o3)));
    }
    *(float4*)(out + (((size_t)c * 8 + b) * 128 + oy) * 128 + 4 * qx) =
        make_float4(o0, o1, o2, o3);
}

extern "C" void kernel_launch(void* const* d_in, const int* in_sizes, int n_in,
                              void* d_out, int out_size, void* d_ws, size_t ws_size,
                              hipStream_t stream) {
    const float* x       = (const float*)d_in[0];
    const float* w_sigma = (const float*)d_in[1];
    const float* w_fc    = (const float*)d_in[2];
    const float* b_fc    = (const float*)d_in[3];
    float* out = (float*)d_out;
    float* ws  = (float*)d_ws;
    const unsigned short* wtb = (const unsigned short*)(ws + 512);

    // big path needs: 16384 floats header + 8*65536*64 bf16 = 67174400 bytes
    const size_t need = 16384u * 4u + (size_t)8 * 65536 * 64 * 2;
    if (ws_size >= need) {
        unsigned short* xbf = (unsigned short*)(ws + 16384);
        prep_cvt_kernel<<<8193, 256, 0, stream>>>(x, w_sigma, ws, xbf);
        conv_lds_kernel<<<dim3(8, 32, 8), 256, 0, stream>>>(xbf, wtb, ws);
    } else {
        prep_kernel<<<72, 256, 0, stream>>>(w_sigma, ws);
        conv_mfma_kernel<<<dim3(8, 32, 8), 256, 0, stream>>>(x, wtb, ws);
    }
    sigma_kernel<<<1, 64, 0, stream>>>(ws, w_fc, b_fc, ws + 256);
    blur_kernel<<<dim3(16, 8, 64), 256, 0, stream>>>(x, ws + 256, out);
}

// Round 4
// 254.790 us; speedup vs baseline: 1.1326x; 1.1326x over previous
//
#include <hip/hip_runtime.h>
#include <math.h>

// B=8, C=64, H=W=256. conv_sigma: OC=32, VALID 3x3 -> 254x254 (bf16 MFMA).
// blur: stride 2, reflect pad 1, sigma/kern precomputed by sigma_kernel.
//
// ws layout (float index): acc[0,256) ; kparams [256,288) ; wtb bf16 @ float-ofs 512
//   wtb[tap][oc][ic] (9*32*64 ushorts = 36 KB), ic-contiguous for B-frags.

typedef __attribute__((ext_vector_type(8))) short s8v;   // 8 bf16
typedef __attribute__((ext_vector_type(4))) float f4v;   // 4 f32

static __device__ inline unsigned short f2bf(float f) {
    union { float f; unsigned int u; } v; v.f = f;
    unsigned int u = v.u;
    unsigned int r = u + 0x7FFFu + ((u >> 16) & 1u);
    return (unsigned short)(r >> 16);
}

// pack 2 f32 -> 2 bf16 (RNE) in one instruction; lo = a, hi = b
static __device__ inline unsigned int pk_bf16(float a, float b) {
    unsigned int r;
    asm("v_cvt_pk_bf16_f32 %0, %1, %2" : "=v"(r) : "v"(a), "v"(b));
    return r;
}

// ---------------- prep: zero acc + weights -> bf16 [tap][oc][ic] ----------------
__global__ void prep_kernel(const float* __restrict__ w, float* __restrict__ ws) {
    int i = blockIdx.x * blockDim.x + threadIdx.x;
    if (i < 256) ws[i] = 0.f;
    if (i < 9 * 32 * 64) {
        int ic  = i & 63;
        int oc  = (i >> 6) & 31;
        int tap = i >> 11;
        unsigned short* wtb = (unsigned short*)(ws + 512);
        wtb[i] = f2bf(w[oc * 576 + ic * 9 + tap]);
    }
}

// ---------------- conv 3x3 VALID (bf16 MFMA) + relu + spatial reduce ----------------
// grid (8 bx, 32 by, 8 b), block 256 = 4 waves. Block: 8 oy x 32 ox x 32 oc.
// LDS slab: 10 rows x 37 px x 64 ic bf16, [pixel][ic], XOR-swizzled 16B chunks
// (slot = ic_oct ^ ((p>>1)&7); read side = 2 lanes/bank = free per m136).
//
// Staging is latency-bound unless all 24 dwordx4 stay in flight together:
// the r2 build sank them into the convert loop (VGPR stayed 68, ~4KB in
// flight/wave). sched_barrier(0) + memory-clobber fence pins the
// issue-all-then-convert schedule (~24KB in flight/wave).
__global__ __launch_bounds__(256, 3) void conv_mfma_kernel(
        const float* __restrict__ x, const unsigned short* __restrict__ wtb,
        float* __restrict__ acc_out) {
    __shared__ __align__(16) unsigned char sx[370 * 128];  // 47360 B
    __shared__ float sred[4][32];

    const int bx = blockIdx.x, by = blockIdx.y, b = blockIdx.z;
    const int ox0 = bx * 32, oy0 = by * 8;
    const int tid = threadIdx.x;
    const int lane = tid & 63, w = tid >> 6;
    const int m = lane & 15, q = lane >> 4;

    // ---- stage phase 1: issue ALL 24 global float4 loads back-to-back ----
    // item i -> ch = i%9 (fastest: coalesced), yy = (i/9)%10, r4 = i/90 (ic quad)
    // Addresses clamped in-bounds; clamped slots feed only epilogue-masked outputs.
    const float* xb = x + (size_t)b * 64 * 65536;
    float4 va[6][4];
    int   pj[6];
    int   r4a[6];
    bool  vld[6];
#pragma unroll
    for (int k = 0; k < 6; ++k) {
        int i  = tid + k * 256;
        int ch = i % 9;
        int t9 = i / 9;
        int yy = t9 % 10;
        int r4 = t9 / 10;
        int y  = oy0 + yy;  if (y > 255) y = 255;
        int xc = ox0 + ch * 4;  if (xc > 252) xc = 252;
        const float* src = xb + (size_t)((r4 & 15) << 2) * 65536 + y * 256 + xc;
        va[k][0] = *(const float4*)(src);
        va[k][1] = *(const float4*)(src + 65536);
        va[k][2] = *(const float4*)(src + 131072);
        va[k][3] = *(const float4*)(src + 196608);
        pj[k]  = yy * 37 + ch * 4;
        r4a[k] = r4;
        vld[k] = (i < 1440);
    }

    // ---- B-frag prefetch for tap 0 (also pinned before the fence) ----
    const unsigned short* wB = wtb + m * 64 + q * 8;
    s8v bc0 = *(const s8v*)(wB);               // kc0, oc m
    s8v bc1 = *(const s8v*)(wB + 1024);        // kc0, oc 16+m
    s8v bc2 = *(const s8v*)(wB + 32);          // kc1, oc m
    s8v bc3 = *(const s8v*)(wB + 1024 + 32);   // kc1, oc 16+m

    // ---- fence: no load may be sunk past this point ----
    __builtin_amdgcn_sched_barrier(0);
    asm volatile("" ::: "memory");

    // ---- stage phase 2: convert + LDS write ----
#pragma unroll
    for (int k = 0; k < 6; ++k) {
        if (vld[k]) {
            int r4 = r4a[k];
            const float* a0 = (const float*)&va[k][0];
            const float* a1 = (const float*)&va[k][1];
            const float* a2 = (const float*)&va[k][2];
            const float* a3 = (const float*)&va[k][3];
#pragma unroll
            for (int j = 0; j < 4; ++j) {
                int p = pj[k] + j;
                unsigned int lo = pk_bf16(a0[j], a1[j]);   // ic 4r4, 4r4+1
                unsigned int hi = pk_bf16(a2[j], a3[j]);   // ic 4r4+2, 4r4+3
                int cw = (r4 >> 1) ^ ((p >> 1) & 7);
                *(uint2*)(sx + p * 128 + cw * 16 + (r4 & 1) * 8) = make_uint2(lo, hi);
            }
        }
    }
    __syncthreads();

    // ---- K-loop: fully unrolled 9 taps, B-frags 2-deep software pipelined ----
    f4v acc[4][2];
#pragma unroll
    for (int mt = 0; mt < 4; ++mt)
#pragma unroll
        for (int nt = 0; nt < 2; ++nt) acc[mt][nt] = (f4v)0.f;

    int pb[4];
#pragma unroll
    for (int mt = 0; mt < 4; ++mt)
        pb[mt] = (2 * w + (mt >> 1)) * 37 + (mt & 1) * 16 + m;

#pragma unroll
    for (int t = 0; t < 9; ++t) {
        const int off = (t / 3) * 37 + (t % 3);   // compile-time tap offset
        s8v bn0, bn1, bn2, bn3;
        if (t < 8) {                               // compile-time branch
            const unsigned short* wN = wB + (t + 1) * 2048;
            bn0 = *(const s8v*)(wN);
            bn1 = *(const s8v*)(wN + 1024);
            bn2 = *(const s8v*)(wN + 32);
            bn3 = *(const s8v*)(wN + 1024 + 32);
        }
#pragma unroll
        for (int mt = 0; mt < 4; ++mt) {
            int p  = pb[mt] + off;
            int q0 = q ^ ((p >> 1) & 7);
            s8v afr = *(const s8v*)(sx + p * 128 + q0 * 16);
            acc[mt][0] = __builtin_amdgcn_mfma_f32_16x16x32_bf16(afr, bc0, acc[mt][0], 0, 0, 0);
            acc[mt][1] = __builtin_amdgcn_mfma_f32_16x16x32_bf16(afr, bc1, acc[mt][1], 0, 0, 0);
        }
#pragma unroll
        for (int mt = 0; mt < 4; ++mt) {
            int p  = pb[mt] + off;
            int q1 = (4 + q) ^ ((p >> 1) & 7);
            s8v afr = *(const s8v*)(sx + p * 128 + q1 * 16);
            acc[mt][0] = __builtin_amdgcn_mfma_f32_16x16x32_bf16(afr, bc2, acc[mt][0], 0, 0, 0);
            acc[mt][1] = __builtin_amdgcn_mfma_f32_16x16x32_bf16(afr, bc3, acc[mt][1], 0, 0, 0);
        }
        if (t < 8) { bc0 = bn0; bc1 = bn1; bc2 = bn2; bc3 = bn3; }
    }

    // ---- epilogue: relu + mask invalid pixels + reduce ----
    // D layout: col(oc) = lane&15, row(pixel-x) = (lane>>4)*4 + reg
    float s0 = 0.f, s1 = 0.f;
#pragma unroll
    for (int mt = 0; mt < 4; ++mt) {
        int oy = oy0 + 2 * w + (mt >> 1);
        int oxb = ox0 + (mt & 1) * 16 + q * 4;
#pragma unroll
        for (int reg = 0; reg < 4; ++reg) {
            bool val = (oxb + reg < 254) && (oy < 254);
            if (val) {
                s0 += fmaxf(acc[mt][0][reg], 0.f);
                s1 += fmaxf(acc[mt][1][reg], 0.f);
            }
        }
    }
    s0 += __shfl_xor(s0, 16, 64); s0 += __shfl_xor(s0, 32, 64);
    s1 += __shfl_xor(s1, 16, 64); s1 += __shfl_xor(s1, 32, 64);
    if (lane < 16) { sred[w][lane] = s0; sred[w][16 + lane] = s1; }
    __syncthreads();
    if (tid < 32)
        atomicAdd(&acc_out[b * 32 + tid],
                  sred[0][tid] + sred[1][tid] + sred[2][tid] + sred[3][tid]);
}

// ---------------- sigma tail: fc + sigmoid + gaussian taps, once per batch ----------------
// 1 block x 64 threads: 8 lanes per b reduce the 32-wide fc dot.
__global__ void sigma_kernel(const float* __restrict__ acc, const float* __restrict__ wfc,
                             const float* __restrict__ bfc, float* __restrict__ kout) {
    int t = threadIdx.x;
    int b = t >> 3, j = t & 7;
    float s = 0.f;
#pragma unroll
    for (int i = 0; i < 4; ++i) s += acc[b * 32 + j + i * 8] * wfc[j + i * 8];
    s += __shfl_xor(s, 4, 8);
    s += __shfl_xor(s, 2, 8);
    s += __shfl_xor(s, 1, 8);
    if (j == 0) {
        float z = s * (1.0f / (254.0f * 254.0f)) + bfc[0];
        float sig = 1.0f / (1.0f + __expf(-z));
        float ss = fmaxf(sig, 1e-4f);
        float inv2 = 0.5f / (ss * ss);
        float e1 = __expf(-inv2);
        float e2 = __expf(-2.0f * inv2);
        float inv_norm = 1.0f / (1.0f + 4.0f * e1 + 4.0f * e2);
        kout[b * 4 + 0] = inv_norm;           // center
        kout[b * 4 + 1] = e1 * inv_norm;      // edge
        kout[b * 4 + 2] = e2 * inv_norm;      // diagonal
    }
}

// ---------------- blur: stride-2 3x3 with precomputed taps ----------------
// grid (16 oy-blocks, 8 b, 64 c), block 256 = 32 x-threads x 8 oy.
__global__ __launch_bounds__(256) void blur_kernel(
        const float* __restrict__ x, const float* __restrict__ kp,
        float* __restrict__ out) {
    const int c = blockIdx.z, b = blockIdx.y;
    const int tid = threadIdx.x;
    const int qx = tid & 31;                 // 4-output group
    const int oy = blockIdx.x * 8 + (tid >> 5);

    const float kC = kp[b * 4 + 0];
    const float kE = kp[b * 4 + 1];
    const float kD = kp[b * 4 + 2];

    const float* xb = x + ((size_t)(b * 64 + c)) * 65536;

    float o0 = 0.f, o1 = 0.f, o2 = 0.f, o3 = 0.f;
#pragma unroll
    for (int dy = 0; dy < 3; ++dy) {
        int iy = 2 * oy + dy - 1;
        if (iy < 0) iy = 1;                   // reflect
        const float* row = xb + iy * 256;
        const float4 f0 = *(const float4*)(row + 8 * qx);
        const float4 f1 = *(const float4*)(row + 8 * qx + 4);
        float lf = __shfl_up(f1.w, 1, 64);    // left neighbor's last element
        const float sm1 = (qx == 0) ? f0.y : lf;   // reflect at x=-1 -> x=1
        const float ka = (dy == 1) ? kE : kD;
        const float kb = (dy == 1) ? kC : kE;
        const float kc2 = (dy == 1) ? kE : kD;
        o0 = fmaf(ka, sm1,  fmaf(kb, f0.x, fmaf(kc2, f0.y, o0)));
        o1 = fmaf(ka, f0.y, fmaf(kb, f0.z, fmaf(kc2, f0.w, o1)));
        o2 = fmaf(ka, f0.w, fmaf(kb, f1.x, fmaf(kc2, f1.y, o2)));
        o3 = fmaf(ka, f1.y, fmaf(kb, f1.z, fmaf(kc2, f1.w, o3)));
    }
    *(float4*)(out + (((size_t)c * 8 + b) * 128 + oy) * 128 + 4 * qx) =
        make_float4(o0, o1, o2, o3);
}

extern "C" void kernel_launch(void* const* d_in, const int* in_sizes, int n_in,
                              void* d_out, int out_size, void* d_ws, size_t ws_size,
                              hipStream_t stream) {
    const float* x       = (const float*)d_in[0];
    const float* w_sigma = (const float*)d_in[1];
    const float* w_fc    = (const float*)d_in[2];
    const float* b_fc    = (const float*)d_in[3];
    float* out = (float*)d_out;
    float* ws  = (float*)d_ws;
    const unsigned short* wtb = (const unsigned short*)(ws + 512);

    prep_kernel<<<72, 256, 0, stream>>>(w_sigma, ws);
    conv_mfma_kernel<<<dim3(8, 32, 8), 256, 0, stream>>>(x, wtb, ws);
    sigma_kernel<<<1, 64, 0, stream>>>(ws, w_fc, b_fc, ws + 256);
    blur_kernel<<<dim3(16, 8, 64), 256, 0, stream>>>(x, ws + 256, out);
}